// Round 9
// baseline (316.507 us; speedup 1.0000x reference)
//
#include <hip/hip_runtime.h>
#include <math.h>

#define HH 64
#define HF 32                          // features per plane (lo/hi split)
// Bucket = col >> 8 (256 nodes per bucket). Requires N <= 65536 (N=50000 here),
// also required by the 16-bit row packing in pairbuf, and NB <= 256.
#define BSH 8
#define BSZ 256
#define HBLK 256                       // blocks participating in histogram/scatter
#define HSTRIDE (HBLK * 256)           // edge-slice stride (must match in both passes)

typedef _Float16 half_t;
typedef _Float16 half2_t __attribute__((ext_vector_type(2)));
typedef _Float16 half4_t __attribute__((ext_vector_type(4)));

// ---------------- layer-1 GEMM (fp32 x @ W1 -> fp16 split planes) + histogram ----
__global__ __launch_bounds__(256, 3)
void k_gemm1_hist(const float* __restrict__ x, const float* __restrict__ W,
                  half_t* __restrict__ lo, half_t* __restrict__ hi, int n,
                  const int* __restrict__ col, int E, int* __restrict__ ph) {
    constexpr int FIN = 128;
    constexpr int KC = 32;
    __shared__ __align__(16) float Ws[FIN][HH];
    __shared__ __align__(16) float xs_t[KC][68];
    __shared__ int hh[BSZ];
    const int tid = threadIdx.x;
    const int bid = blockIdx.x;

    // ---- histogram slice (blocks 0..HBLK-1) ----
    if (bid < HBLK) {
        hh[tid] = 0;
        __syncthreads();
        for (int e = bid * 256 + tid; e < E; e += HSTRIDE)
            atomicAdd(&hh[col[e] >> BSH], 1);
        __syncthreads();
        ph[bid * BSZ + tid] = hh[tid];
    }

    // ---- GEMM tile (verified round-4 structure) ----
    const int tx = tid & 15;
    const int ty = tid >> 4;
    const int node0 = bid * 64;
    if (node0 >= n) return;

    for (int i = tid * 4; i < FIN * HH; i += 1024)
        *(float4*)&Ws[0][i] = *(const float4*)&W[i];

    float acc[4][4] = {};
    const int rr0 = tid >> 3;
    const int cc  = (tid & 7) * 4;

    for (int kc = 0; kc < FIN; kc += KC) {
        __syncthreads();
        for (int rr = rr0; rr < 64; rr += 32) {
            float4 v = make_float4(0.f, 0.f, 0.f, 0.f);
            if (node0 + rr < n) v = *(const float4*)&x[(size_t)(node0 + rr) * FIN + kc + cc];
            xs_t[cc + 0][rr] = v.x;
            xs_t[cc + 1][rr] = v.y;
            xs_t[cc + 2][rr] = v.z;
            xs_t[cc + 3][rr] = v.w;
        }
        __syncthreads();
#pragma unroll 4
        for (int k = 0; k < KC; ++k) {
            float4 a4 = *(const float4*)&xs_t[k][ty * 4];
            float4 b4 = *(const float4*)&Ws[kc + k][tx * 4];
            acc[0][0] = fmaf(a4.x, b4.x, acc[0][0]);
            acc[0][1] = fmaf(a4.x, b4.y, acc[0][1]);
            acc[0][2] = fmaf(a4.x, b4.z, acc[0][2]);
            acc[0][3] = fmaf(a4.x, b4.w, acc[0][3]);
            acc[1][0] = fmaf(a4.y, b4.x, acc[1][0]);
            acc[1][1] = fmaf(a4.y, b4.y, acc[1][1]);
            acc[1][2] = fmaf(a4.y, b4.z, acc[1][2]);
            acc[1][3] = fmaf(a4.y, b4.w, acc[1][3]);
            acc[2][0] = fmaf(a4.z, b4.x, acc[2][0]);
            acc[2][1] = fmaf(a4.z, b4.y, acc[2][1]);
            acc[2][2] = fmaf(a4.z, b4.z, acc[2][2]);
            acc[2][3] = fmaf(a4.z, b4.w, acc[2][3]);
            acc[3][0] = fmaf(a4.w, b4.x, acc[3][0]);
            acc[3][1] = fmaf(a4.w, b4.y, acc[3][1]);
            acc[3][2] = fmaf(a4.w, b4.z, acc[3][2]);
            acc[3][3] = fmaf(a4.w, b4.w, acc[3][3]);
        }
    }
#pragma unroll
    for (int i = 0; i < 4; ++i) {
        int node = node0 + ty * 4 + i;
        if (node < n) {
            half4_t o = {(half_t)acc[i][0], (half_t)acc[i][1],
                         (half_t)acc[i][2], (half_t)acc[i][3]};
            if (tx < 8) *(half4_t*)&lo[(size_t)node * HF + tx * 4]        = o;
            else        *(half4_t*)&hi[(size_t)node * HF + tx * 4 - 32]   = o;
        }
    }
}

// ---------------- scatter: atomic-free via ph-prefix (R6-verified) ------------
__global__ __launch_bounds__(256) void k_bscatter2(const int* __restrict__ row,
                                                   const int* __restrict__ col, int E,
                                                   const int* __restrict__ ph,
                                                   int* __restrict__ base,
                                                   int* __restrict__ pair, int nb) {
    __shared__ int cur[BSZ];
    __shared__ int ssc[BSZ];
    const int b = blockIdx.x;
    const int t = threadIdx.x;
    int before = 0, total = 0;
    for (int k = 0; k < HBLK; ++k) {
        int v = ph[k * BSZ + t];
        total += v;
        if (k < b) before += v;
    }
    ssc[t] = total;
    __syncthreads();
    for (int d = 1; d < 256; d <<= 1) {
        int x2 = ssc[t];
        if (t >= d) x2 += ssc[t - d];
        __syncthreads();
        ssc[t] = x2;
        __syncthreads();
    }
    int excl = ssc[t] - total;
    cur[t] = excl + before;
    if (b == 0) {
        if (t < nb) base[t] = excl;
        if (t == 0) base[nb] = E;
    }
    __syncthreads();
    for (int e = b * 256 + t; e < E; e += HSTRIDE) {
        int c = col[e];
        int pos = atomicAdd(&cur[c >> BSH], 1);   // LDS atomic only
        pair[pos] = (row[e] & 0xFFFF) | ((c & (BSZ - 1)) << 16);
    }
}

// ---------------- per-bucket fine CSR build (unchanged, round-4 verified) -----
__global__ __launch_bounds__(256) void k_bcsr(const int* __restrict__ pair,
                                              const int* __restrict__ base,
                                              int* __restrict__ rowptr,
                                              int* __restrict__ cnt,
                                              float* __restrict__ dinv,
                                              int* __restrict__ csr, int n) {
    __shared__ int lcnt[BSZ];
    __shared__ int ssc[BSZ];
    __shared__ int lcur[BSZ];
    const int b = blockIdx.x;
    const int t = threadIdx.x;
    const int nd0 = b << BSH;
    const int e0 = base[b];
    const int e1 = base[b + 1];

    lcnt[t] = 0;
    __syncthreads();
    for (int e = e0 + t; e < e1; e += 256)
        atomicAdd(&lcnt[(pair[e] >> 16) & (BSZ - 1)], 1);
    __syncthreads();
    int v = lcnt[t];
    ssc[t] = v;
    __syncthreads();
    for (int d = 1; d < 256; d <<= 1) {
        int x2 = ssc[t];
        if (t >= d) x2 += ssc[t - d];
        __syncthreads();
        ssc[t] = x2;
        __syncthreads();
    }
    int excl = ssc[t] - v;
    lcur[t] = e0 + excl;
    int node = nd0 + t;
    if (node < n) {
        rowptr[node] = e0 + excl;
        cnt[node]    = v;
        dinv[node]   = rsqrtf((float)(v + 1));
    }
    __syncthreads();
    for (int e = e0 + t; e < e1; e += 256) {
        int pr = pair[e];
        int pos = atomicAdd(&lcur[(pr >> 16) & (BSZ - 1)], 1);
        csr[pos] = pr & 0xFFFF;
    }
}

// ---------------- dense transform layers 2-3: split-plane in/out --------------
// Input is PRE-NORM split h + per-pass ss; staging applies inv*relu (inv>0 so
// relu(v*inv) == inv*relu(v)). Output scaled by dinv, written as split planes.
template<int FIN>
__global__ __launch_bounds__(256, 4)
void k_gemm(const half_t* __restrict__ xlo, const half_t* __restrict__ xhi,
            const float* __restrict__ ssLo, const float* __restrict__ ssHi,
            const float* __restrict__ W, const float* __restrict__ dinv,
            half_t* __restrict__ olo, half_t* __restrict__ ohi, int n) {
    constexpr int KC = 32;
    __shared__ __align__(16) float Ws[FIN][HH];
    __shared__ __align__(16) float xs_t[KC][68];
    const int tid = threadIdx.x;
    const int tx = tid & 15;
    const int ty = tid >> 4;
    const int node0 = blockIdx.x * 64;
    if (node0 >= n) return;

    for (int i = tid * 4; i < FIN * HH; i += 1024)
        *(float4*)&Ws[0][i] = *(const float4*)&W[i];

    float acc[4][4] = {};
    const int rr0 = tid >> 3;
    const int cc  = (tid & 7) * 4;

    for (int kc = 0; kc < FIN; kc += KC) {
        __syncthreads();
        for (int rr = rr0; rr < 64; rr += 32) {
            int r = node0 + rr;
            float4 v = make_float4(0.f, 0.f, 0.f, 0.f);
            if (r < n) {
                float invr = 1.f / fmaxf(sqrtf(ssLo[r] + ssHi[r]), 1e-12f);
                int f = kc + cc;
                const half_t* src = (f < 32) ? xlo : xhi;
                half4_t hv = *(const half4_t*)&src[(size_t)r * HF + (f & 31)];
                v = make_float4(invr * fmaxf((float)hv.x, 0.f),
                                invr * fmaxf((float)hv.y, 0.f),
                                invr * fmaxf((float)hv.z, 0.f),
                                invr * fmaxf((float)hv.w, 0.f));
            }
            xs_t[cc + 0][rr] = v.x;
            xs_t[cc + 1][rr] = v.y;
            xs_t[cc + 2][rr] = v.z;
            xs_t[cc + 3][rr] = v.w;
        }
        __syncthreads();
#pragma unroll 4
        for (int k = 0; k < KC; ++k) {
            float4 a4 = *(const float4*)&xs_t[k][ty * 4];
            float4 b4 = *(const float4*)&Ws[kc + k][tx * 4];
            acc[0][0] = fmaf(a4.x, b4.x, acc[0][0]);
            acc[0][1] = fmaf(a4.x, b4.y, acc[0][1]);
            acc[0][2] = fmaf(a4.x, b4.z, acc[0][2]);
            acc[0][3] = fmaf(a4.x, b4.w, acc[0][3]);
            acc[1][0] = fmaf(a4.y, b4.x, acc[1][0]);
            acc[1][1] = fmaf(a4.y, b4.y, acc[1][1]);
            acc[1][2] = fmaf(a4.y, b4.z, acc[1][2]);
            acc[1][3] = fmaf(a4.y, b4.w, acc[1][3]);
            acc[2][0] = fmaf(a4.z, b4.x, acc[2][0]);
            acc[2][1] = fmaf(a4.z, b4.y, acc[2][1]);
            acc[2][2] = fmaf(a4.z, b4.z, acc[2][2]);
            acc[2][3] = fmaf(a4.z, b4.w, acc[2][3]);
            acc[3][0] = fmaf(a4.w, b4.x, acc[3][0]);
            acc[3][1] = fmaf(a4.w, b4.y, acc[3][1]);
            acc[3][2] = fmaf(a4.w, b4.z, acc[3][2]);
            acc[3][3] = fmaf(a4.w, b4.w, acc[3][3]);
        }
    }
#pragma unroll
    for (int i = 0; i < 4; ++i) {
        int node = node0 + ty * 4 + i;
        if (node < n) {
            float d = dinv[node];
            half4_t o = {(half_t)(acc[i][0] * d), (half_t)(acc[i][1] * d),
                         (half_t)(acc[i][2] * d), (half_t)(acc[i][3] * d)};
            if (tx < 8) *(half4_t*)&olo[(size_t)node * HF + tx * 4]      = o;
            else        *(half4_t*)&ohi[(size_t)node * HF + tx * 4 - 32] = o;
        }
    }
}

// ---------------- gather: quarter-wave shfl (R4-verified) on SPLIT planes ------
// pass = bid&1 selects the 3.2MB lo/hi plane -> fits one XCD's 4MB L2; even/odd
// bids land on even/odd XCDs (round-robin), so each XCD's random row reads hit
// an L2-resident working set. Writes PRE-NORM v (fp16) + per-pass ss[node];
// consumers apply inv*relu. Row = 64B: 16 lanes x half2. Epilogue: 2-step acc
// reduce + 4-step ss reduce (lanes 0-15).
template<bool WEIGHTED>
__global__ __launch_bounds__(256) void k_gather_s(const half_t* __restrict__ lin_lo,
                                                  const half_t* __restrict__ lin_hi,
                                                  const int* __restrict__ csr,
                                                  const int* __restrict__ rowptr,
                                                  const int* __restrict__ cnt,
                                                  const float* __restrict__ dinv,
                                                  const float* __restrict__ b,
                                                  half_t* __restrict__ h_lo,
                                                  half_t* __restrict__ h_hi,
                                                  float* __restrict__ ssLo,
                                                  float* __restrict__ ssHi, int n) {
    const int pass = blockIdx.x & 1;
    const int grp  = blockIdx.x >> 1;
    const int lane = threadIdx.x & 63;
    const int node = grp * 4 + (threadIdx.x >> 6);
    if (node >= n) return;
    const half_t* __restrict__ lin = pass ? lin_hi : lin_lo;
    half_t* __restrict__ ho  = pass ? h_hi : h_lo;
    float*  __restrict__ ssp = pass ? ssHi : ssLo;

    const int q   = lane >> 4;
    const int fl2 = (lane & 15) * 2;       // half2 feature offset within plane
    const int bf  = pass * HF + fl2;       // bias offset (global feature index)
    int start = rowptr[node];
    int end = start + cnt[node];
    float di = dinv[node];

    float ax0 = 0.f, ay0 = 0.f, ax1 = 0.f, ay1 = 0.f;

    for (int base = start; base < end; base += 64) {
        int m = end - base; if (m > 64) m = 64;
        int idx = base + lane;
        int   sv = (idx < end) ? csr[idx] : 0;
        float wv;
        if (WEIGHTED) wv = (idx < end) ? dinv[sv] : 0.f;
        else          wv = (idx < end) ? 1.f : 0.f;
        for (int j = 0; j < m; j += 16) {
            int l = j + q * 4;
            int   s0 = __shfl(sv, l, 64);
            int   s1 = __shfl(sv, l + 1, 64);
            int   s2 = __shfl(sv, l + 2, 64);
            int   s3 = __shfl(sv, l + 3, 64);
            float w0 = __shfl(wv, l, 64);
            float w1 = __shfl(wv, l + 1, 64);
            float w2 = __shfl(wv, l + 2, 64);
            float w3 = __shfl(wv, l + 3, 64);
            half2_t v0 = *(const half2_t*)&lin[(size_t)s0 * HF + fl2];
            half2_t v1 = *(const half2_t*)&lin[(size_t)s1 * HF + fl2];
            half2_t v2 = *(const half2_t*)&lin[(size_t)s2 * HF + fl2];
            half2_t v3 = *(const half2_t*)&lin[(size_t)s3 * HF + fl2];
            ax0 = fmaf(w0, (float)v0.x, ax0); ay0 = fmaf(w0, (float)v0.y, ay0);
            ax1 = fmaf(w1, (float)v1.x, ax1); ay1 = fmaf(w1, (float)v1.y, ay1);
            ax0 = fmaf(w2, (float)v2.x, ax0); ay0 = fmaf(w2, (float)v2.y, ay0);
            ax1 = fmaf(w3, (float)v3.x, ax1); ay1 = fmaf(w3, (float)v3.y, ay1);
        }
    }
    float ax = ax0 + ax1, ay = ay0 + ay1;
    ax += __shfl_xor(ax, 16, 64); ay += __shfl_xor(ay, 16, 64);
    ax += __shfl_xor(ax, 32, 64); ay += __shfl_xor(ay, 32, 64);
    // self-loop (added once, post-reduce; only q==0 result is used)
    half2_t self = *(const half2_t*)&lin[(size_t)node * HF + fl2];
    float sw = WEIGHTED ? di : 1.f;
    ax = fmaf(sw, (float)self.x, ax);
    ay = fmaf(sw, (float)self.y, ay);
    // bias; store PRE-NORM value + ss partial (norm applied by consumer)
    float vx = fmaf(di, ax, b[bf]);
    float vy = fmaf(di, ay, b[bf + 1]);
    float ss = vx * vx + vy * vy;
    ss += __shfl_xor(ss, 1, 64);
    ss += __shfl_xor(ss, 2, 64);
    ss += __shfl_xor(ss, 4, 64);
    ss += __shfl_xor(ss, 8, 64);
    if (q == 0) {
        half2_t o = {(half_t)vx, (half_t)vy};
        *(half2_t*)&ho[(size_t)node * HF + fl2] = o;
        if (lane == 0) ssp[node] = ss;
    }
}

// ---------------- fused normalize + pool + classifier: one block per graph ----
// Reads pre-norm split h3 + ss; writes node_emb (required output) and pools.
__global__ __launch_bounds__(256) void k_poolfinal(const half_t* __restrict__ h_lo,
                                                   const half_t* __restrict__ h_hi,
                                                   const float* __restrict__ ssLo,
                                                   const float* __restrict__ ssHi,
                                                   const int* __restrict__ batch,
                                                   const float* __restrict__ Wm,
                                                   const float* __restrict__ bm,
                                                   float* __restrict__ logits,
                                                   float* __restrict__ probs,
                                                   float* __restrict__ node_emb,
                                                   float* __restrict__ graph_emb, int n) {
    __shared__ float part[4][HH];
    __shared__ float semb[HH];
    __shared__ float slog[16];
    const int g = blockIdx.x;
    const int tid = threadIdx.x;
    const int lane = tid & 63, w = tid >> 6;

    int lo = 0, hi = n;
    while (lo < hi) { int mid = (lo + hi) >> 1; if (batch[mid] < g) lo = mid + 1; else hi = mid; }
    const int s = lo;
    hi = n;
    while (lo < hi) { int mid = (lo + hi) >> 1; if (batch[mid] < g + 1) lo = mid + 1; else hi = mid; }
    const int e2 = lo;

    float acc = 0.f;
    for (int i = s + w; i < e2; i += 4) {
        float invr = 1.f / fmaxf(sqrtf(ssLo[i] + ssHi[i]), 1e-12f);
        half_t hv = (lane < HF) ? h_lo[(size_t)i * HF + lane]
                                : h_hi[(size_t)i * HF + lane - HF];
        float emb = invr * fmaxf((float)hv, 0.f);
        node_emb[(size_t)i * HH + lane] = emb;
        acc += emb;
    }
    part[w][lane] = acc;
    __syncthreads();
    if (tid < HH) {
        float m = part[0][tid] + part[1][tid] + part[2][tid] + part[3][tid];
        m /= fmaxf((float)(e2 - s), 1.f);
        graph_emb[(size_t)g * HH + tid] = m;
        semb[tid] = m;
    }
    __syncthreads();
    if (tid < 10) {
        float a2 = bm[tid];
        for (int k = 0; k < HH; ++k) a2 = fmaf(semb[k], Wm[k * 10 + tid], a2);
        slog[tid] = a2;
    }
    __syncthreads();
    if (tid < 10) {
        float mx = -1e30f;
        for (int j = 0; j < 10; ++j) mx = fmaxf(mx, slog[j]);
        float den = 0.f;
        for (int j = 0; j < 10; ++j) den += __expf(slog[j] - mx);
        float lg = slog[tid];
        logits[g * 10 + tid] = lg;
        probs[g * 10 + tid] = __expf(lg - mx) / den;
    }
}

// ---------------- launch ----------------

extern "C" void kernel_launch(void* const* d_in, const int* in_sizes, int n_in,
                              void* d_out, int out_size, void* d_ws, size_t ws_size,
                              hipStream_t stream) {
    const float* x     = (const float*)d_in[0];
    const int*   ei    = (const int*)  d_in[1];
    const int*   batch = (const int*)  d_in[2];
    const float* W1 = (const float*)d_in[3];  const float* b1 = (const float*)d_in[4];
    const float* W2 = (const float*)d_in[5];  const float* b2 = (const float*)d_in[6];
    const float* W3 = (const float*)d_in[7];  const float* b3 = (const float*)d_in[8];
    const float* Wm = (const float*)d_in[9];  const float* bm = (const float*)d_in[10];

    const int N = in_sizes[2];
    const int E = in_sizes[1] / 2;
    const int G = (out_size - N * HH) / (2 * 10 + HH);
    const int NB = (N + BSZ - 1) >> BSH;

    const int* row = ei;
    const int* col = ei + E;

    float* out       = (float*)d_out;
    float* logits    = out;
    float* probs     = out + (size_t)G * 10;
    float* node_emb  = out + (size_t)2 * G * 10;
    float* graph_emb = node_emb + (size_t)N * HH;

    char* w = (char*)d_ws;
    auto alloc = [&](size_t bytes) { char* p = w; w += (bytes + 255) & ~(size_t)255; return p; };
    float* dinv    = (float*)alloc((size_t)N * 4);
    int*   cnt     = (int*)  alloc((size_t)N * 4);
    int*   rowptr  = (int*)  alloc((size_t)N * 4);
    int*   ph      = (int*)  alloc((size_t)HBLK * BSZ * 4);
    int*   base    = (int*)  alloc((size_t)(NB + 1) * 4);
    int*   pairbuf = (int*)  alloc((size_t)E * 4);
    int*   csr     = (int*)  alloc((size_t)E * 4);
    half_t* A_lo   = (half_t*)alloc((size_t)N * HF * 2);
    half_t* A_hi   = (half_t*)alloc((size_t)N * HF * 2);
    half_t* B_lo   = (half_t*)alloc((size_t)N * HF * 2);
    half_t* B_hi   = (half_t*)alloc((size_t)N * HF * 2);
    float* ssLo    = (float*)alloc((size_t)N * 4);
    float* ssHi    = (float*)alloc((size_t)N * 4);

    const int B = 256;
    dim3 blk(B);
    int node_blocks = (N + 3) / 4;
    int gather_blocks = 2 * node_blocks;     // x2: lo/hi passes on even/odd XCDs
    int gemm_blocks = (N + 63) / 64;
    int g1_blocks = gemm_blocks > HBLK ? gemm_blocks : HBLK;

    k_gemm1_hist<<<g1_blocks, blk, 0, stream>>>(x, W1, A_lo, A_hi, N, col, E, ph);
    k_bscatter2<<<HBLK, blk, 0, stream>>>(row, col, E, ph, base, pairbuf, NB);
    k_bcsr<<<NB, blk, 0, stream>>>(pairbuf, base, rowptr, cnt, dinv, csr, N);

    k_gather_s<true><<<gather_blocks, blk, 0, stream>>>(A_lo, A_hi, csr, rowptr, cnt,
                                                        dinv, b1, B_lo, B_hi, ssLo, ssHi, N);
    k_gemm<64><<<gemm_blocks, blk, 0, stream>>>(B_lo, B_hi, ssLo, ssHi, W2, dinv, A_lo, A_hi, N);
    k_gather_s<false><<<gather_blocks, blk, 0, stream>>>(A_lo, A_hi, csr, rowptr, cnt,
                                                         dinv, b2, B_lo, B_hi, ssLo, ssHi, N);
    k_gemm<64><<<gemm_blocks, blk, 0, stream>>>(B_lo, B_hi, ssLo, ssHi, W3, dinv, A_lo, A_hi, N);
    k_gather_s<false><<<gather_blocks, blk, 0, stream>>>(A_lo, A_hi, csr, rowptr, cnt,
                                                         dinv, b3, B_lo, B_hi, ssLo, ssHi, N);

    k_poolfinal<<<G, blk, 0, stream>>>(B_lo, B_hi, ssLo, ssHi, batch, Wm, bm,
                                       logits, probs, node_emb, graph_emb, N);
}

// Round 10
// 267.812 us; speedup vs baseline: 1.1818x; 1.1818x over previous
//
#include <hip/hip_runtime.h>
#include <math.h>

#define HH 64
// Bucket = col >> 8 (256 nodes per bucket). Assumes N <= 65536 (N=50000 here)
// — also required by the 16-bit row packing in pairbuf.
#define BSH 8
#define BSZ 256

typedef _Float16 half_t;
typedef _Float16 half4_t __attribute__((ext_vector_type(4)));

// ---------------- init ----------------

__global__ void k_init(int* __restrict__ bucket_cnt, float* __restrict__ sums,
                       int nb, int pn) {
    int i = blockIdx.x * blockDim.x + threadIdx.x;
    if (i < nb) bucket_cnt[i] = 0;
    if (i < pn) sums[i] = 0.f;
}

// ---------------- CSR pass A: bucket histogram via LDS (no per-edge global atomics) ----
__global__ __launch_bounds__(256) void k_bhist(const int* __restrict__ col, int E,
                                               int* __restrict__ bucket_cnt, int nb) {
    __shared__ int h[BSZ];
    int t = threadIdx.x;
    h[t] = 0;
    __syncthreads();
    int stride = gridDim.x * blockDim.x;
    for (int e = blockIdx.x * blockDim.x + t; e < E; e += stride)
        atomicAdd(&h[col[e] >> BSH], 1);
    __syncthreads();
    if (t < nb && h[t]) atomicAdd(&bucket_cnt[t], h[t]);
}

// ---------------- CSR pass B: exclusive scan of bucket counts (single block) ----
__global__ __launch_bounds__(256) void k_bscan(const int* __restrict__ bc,
                                               int* __restrict__ base,
                                               int* __restrict__ cursor, int nb) {
    __shared__ int s[256];
    __shared__ int carry_s;
    int t = threadIdx.x;
    if (t == 0) carry_s = 0;
    __syncthreads();
    for (int off = 0; off < nb; off += 256) {
        int i = off + t;
        int v = (i < nb) ? bc[i] : 0;
        s[t] = v;
        __syncthreads();
        for (int d = 1; d < 256; d <<= 1) {
            int x = s[t];
            if (t >= d) x += s[t - d];
            __syncthreads();
            s[t] = x;
            __syncthreads();
        }
        int carry = carry_s;
        int excl = carry + s[t] - v;
        if (i < nb) { base[i] = excl; cursor[i] = excl; }
        int tot = s[255];
        __syncthreads();
        if (t == 0) carry_s = carry + tot;
        __syncthreads();
    }
    if (t == 0) base[nb] = carry_s;
}

// ---------------- CSR pass C: scatter edges into bucket-contiguous packed list ----
// One global atomic per (block,bucket) reservation (~50k total). Packed entry:
// bits 0-15 = row (N < 65536), bits 16-23 = col & 255. Halves pair traffic.
__global__ __launch_bounds__(256) void k_bscatter(const int* __restrict__ row,
                                                  const int* __restrict__ col, int E,
                                                  int* __restrict__ gcursor,
                                                  int* __restrict__ pair, int nb) {
    __shared__ int h[BSZ];
    __shared__ int cur[BSZ];
    int t = threadIdx.x;
    h[t] = 0;
    __syncthreads();
    int stride = gridDim.x * blockDim.x;
    for (int e = blockIdx.x * blockDim.x + t; e < E; e += stride)
        atomicAdd(&h[col[e] >> BSH], 1);
    __syncthreads();
    {
        int c = h[t];
        cur[t] = (t < nb && c > 0) ? atomicAdd(&gcursor[t], c) : 0;
    }
    __syncthreads();
    for (int e = blockIdx.x * blockDim.x + t; e < E; e += stride) {
        int c = col[e];
        int pos = atomicAdd(&cur[c >> BSH], 1);
        pair[pos] = (row[e] & 0xFFFF) | ((c & (BSZ - 1)) << 16);
    }
}

// ---------------- CSR pass D: per-bucket fine CSR build (one block per bucket) ----
// All per-edge atomics are LDS; csr writes confined to the bucket's window.
__global__ __launch_bounds__(256) void k_bcsr(const int* __restrict__ pair,
                                              const int* __restrict__ base,
                                              int* __restrict__ rowptr,
                                              int* __restrict__ cnt,
                                              float* __restrict__ dinv,
                                              int* __restrict__ csr, int n) {
    __shared__ int lcnt[BSZ];
    __shared__ int ssc[BSZ];
    __shared__ int lcur[BSZ];
    const int b = blockIdx.x;
    const int t = threadIdx.x;
    const int nd0 = b << BSH;
    const int e0 = base[b];
    const int e1 = base[b + 1];

    lcnt[t] = 0;
    __syncthreads();
    for (int e = e0 + t; e < e1; e += 256)
        atomicAdd(&lcnt[(pair[e] >> 16) & (BSZ - 1)], 1);
    __syncthreads();
    int v = lcnt[t];
    ssc[t] = v;
    __syncthreads();
    for (int d = 1; d < 256; d <<= 1) {
        int x = ssc[t];
        if (t >= d) x += ssc[t - d];
        __syncthreads();
        ssc[t] = x;
        __syncthreads();
    }
    int excl = ssc[t] - v;
    lcur[t] = e0 + excl;
    int node = nd0 + t;
    if (node < n) {
        rowptr[node] = e0 + excl;
        cnt[node]    = v;
        dinv[node]   = rsqrtf((float)(v + 1));
    }
    __syncthreads();
    for (int e = e0 + t; e < e1; e += 256) {
        int p = pair[e];
        int pos = atomicAdd(&lcur[(p >> 16) & (BSZ - 1)], 1);
        csr[pos] = p & 0xFFFF;
    }
}

// ---------------- dense transform: 64-node tile, fp16-in/out options ----------------
// Accumulation fp32 in registers; LDS tiles fp32. HIN: input is half. HOUT: out half.
template<int FIN, bool SCALE, bool HIN, bool HOUT>
__global__ __launch_bounds__(256, (FIN == 128) ? 3 : 4)
void k_gemm(const void* __restrict__ xin, const float* __restrict__ W,
            const float* __restrict__ dinv, void* __restrict__ out, int n) {
    constexpr int KC = 32;
    constexpr int XS = 68;
    __shared__ __align__(16) float Ws[FIN][HH];
    __shared__ __align__(16) float xs_t[KC][XS];
    const int tid = threadIdx.x;
    const int tx = tid & 15;
    const int ty = tid >> 4;
    const int node0 = blockIdx.x * 64;
    if (node0 >= n) return;

    for (int i = tid * 4; i < FIN * HH; i += 1024)
        *(float4*)&Ws[0][i] = *(const float4*)&W[i];

    float acc[4][4] = {};
    const int rr0 = tid >> 3;
    const int cc  = (tid & 7) * 4;

    for (int kc = 0; kc < FIN; kc += KC) {
        __syncthreads();
        for (int rr = rr0; rr < 64; rr += 32) {
            float4 v = make_float4(0.f, 0.f, 0.f, 0.f);
            if (node0 + rr < n) {
                if constexpr (HIN) {
                    half4_t hv = *(const half4_t*)((const half_t*)xin +
                                   (size_t)(node0 + rr) * FIN + kc + cc);
                    v = make_float4((float)hv.x, (float)hv.y, (float)hv.z, (float)hv.w);
                } else {
                    v = *(const float4*)((const float*)xin +
                                   (size_t)(node0 + rr) * FIN + kc + cc);
                }
            }
            xs_t[cc + 0][rr] = v.x;
            xs_t[cc + 1][rr] = v.y;
            xs_t[cc + 2][rr] = v.z;
            xs_t[cc + 3][rr] = v.w;
        }
        __syncthreads();
#pragma unroll 4
        for (int k = 0; k < KC; ++k) {
            float4 a4 = *(const float4*)&xs_t[k][ty * 4];
            float4 b4 = *(const float4*)&Ws[kc + k][tx * 4];
            acc[0][0] = fmaf(a4.x, b4.x, acc[0][0]);
            acc[0][1] = fmaf(a4.x, b4.y, acc[0][1]);
            acc[0][2] = fmaf(a4.x, b4.z, acc[0][2]);
            acc[0][3] = fmaf(a4.x, b4.w, acc[0][3]);
            acc[1][0] = fmaf(a4.y, b4.x, acc[1][0]);
            acc[1][1] = fmaf(a4.y, b4.y, acc[1][1]);
            acc[1][2] = fmaf(a4.y, b4.z, acc[1][2]);
            acc[1][3] = fmaf(a4.y, b4.w, acc[1][3]);
            acc[2][0] = fmaf(a4.z, b4.x, acc[2][0]);
            acc[2][1] = fmaf(a4.z, b4.y, acc[2][1]);
            acc[2][2] = fmaf(a4.z, b4.z, acc[2][2]);
            acc[2][3] = fmaf(a4.z, b4.w, acc[2][3]);
            acc[3][0] = fmaf(a4.w, b4.x, acc[3][0]);
            acc[3][1] = fmaf(a4.w, b4.y, acc[3][1]);
            acc[3][2] = fmaf(a4.w, b4.z, acc[3][2]);
            acc[3][3] = fmaf(a4.w, b4.w, acc[3][3]);
        }
    }

#pragma unroll
    for (int i = 0; i < 4; ++i) {
        int node = node0 + ty * 4 + i;
        if (node < n) {
            float d = SCALE ? dinv[node] : 1.f;
            float r0 = acc[i][0] * d, r1 = acc[i][1] * d;
            float r2 = acc[i][2] * d, r3 = acc[i][3] * d;
            if constexpr (HOUT) {
                half4_t o = {(half_t)r0, (half_t)r1, (half_t)r2, (half_t)r3};
                *(half4_t*)((half_t*)out + (size_t)node * HH + tx * 4) = o;
            } else {
                *(float4*)((float*)out + (size_t)node * HH + tx * 4) =
                    make_float4(r0, r1, r2, r3);
            }
        }
    }
}

// ---------------- gather: quarter-wave, fp16 rows (128 B/row), fp32 accumulate ----
// WEIGHTED (layer 1): lin unscaled, per-edge weight dinv[src], self weight di.
// else (layers 2-3): linS pre-scaled, weight 1, self weight 1.
// HOUT: write half (feeds next gemm) or float (node_emb output).
// All cross-lane shfls UNCONDITIONAL (uniform exec); range guards in wv only.
template<bool WEIGHTED, bool HOUT>
__global__ __launch_bounds__(256) void k_gather_q(const half_t* __restrict__ lin,
                                                  const int* __restrict__ csr,
                                                  const int* __restrict__ rowptr,
                                                  const int* __restrict__ cnt,
                                                  const float* __restrict__ dinv,
                                                  const float* __restrict__ b,
                                                  void* __restrict__ hout, int n) {
    int node = blockIdx.x * 4 + (threadIdx.x >> 6);
    int lane = threadIdx.x & 63;
    if (node >= n) return;
    const int q  = lane >> 4;          // quarter 0..3
    const int fl = (lane & 15) * 4;    // feature offset (in elements)
    int start = rowptr[node];
    int end = start + cnt[node];
    float di = dinv[node];

    float4 a0 = make_float4(0.f, 0.f, 0.f, 0.f);
    float4 a1 = make_float4(0.f, 0.f, 0.f, 0.f);

    for (int base = start; base < end; base += 64) {
        int m = end - base; if (m > 64) m = 64;
        int idx = base + lane;
        int   sv = (idx < end) ? csr[idx] : 0;
        float wv;
        if (WEIGHTED) wv = (idx < end) ? dinv[sv] : 0.f;   // predicated load: safe
        else          wv = (idx < end) ? 1.f : 0.f;
        for (int j = 0; j < m; j += 16) {
            int l = j + q * 4;                       // <= 63 always
            int   s0 = __shfl(sv, l, 64);            // unconditional, uniform
            int   s1 = __shfl(sv, l + 1, 64);
            int   s2 = __shfl(sv, l + 2, 64);
            int   s3 = __shfl(sv, l + 3, 64);
            float w0 = __shfl(wv, l, 64);
            float w1 = __shfl(wv, l + 1, 64);
            float w2 = __shfl(wv, l + 2, 64);
            float w3 = __shfl(wv, l + 3, 64);
            half4_t v0 = *(const half4_t*)&lin[(size_t)s0 * HH + fl];
            half4_t v1 = *(const half4_t*)&lin[(size_t)s1 * HH + fl];
            half4_t v2 = *(const half4_t*)&lin[(size_t)s2 * HH + fl];
            half4_t v3 = *(const half4_t*)&lin[(size_t)s3 * HH + fl];
            a0.x = fmaf(w0, (float)v0.x, a0.x); a0.y = fmaf(w0, (float)v0.y, a0.y);
            a0.z = fmaf(w0, (float)v0.z, a0.z); a0.w = fmaf(w0, (float)v0.w, a0.w);
            a1.x = fmaf(w1, (float)v1.x, a1.x); a1.y = fmaf(w1, (float)v1.y, a1.y);
            a1.z = fmaf(w1, (float)v1.z, a1.z); a1.w = fmaf(w1, (float)v1.w, a1.w);
            a0.x = fmaf(w2, (float)v2.x, a0.x); a0.y = fmaf(w2, (float)v2.y, a0.y);
            a0.z = fmaf(w2, (float)v2.z, a0.z); a0.w = fmaf(w2, (float)v2.w, a0.w);
            a1.x = fmaf(w3, (float)v3.x, a1.x); a1.y = fmaf(w3, (float)v3.y, a1.y);
            a1.z = fmaf(w3, (float)v3.z, a1.z); a1.w = fmaf(w3, (float)v3.w, a1.w);
        }
    }
    float4 acc = make_float4(a0.x + a1.x, a0.y + a1.y, a0.z + a1.z, a0.w + a1.w);
#pragma unroll
    for (int off = 16; off < 64; off <<= 1) {
        acc.x += __shfl_xor(acc.x, off, 64);
        acc.y += __shfl_xor(acc.y, off, 64);
        acc.z += __shfl_xor(acc.z, off, 64);
        acc.w += __shfl_xor(acc.w, off, 64);
    }
    // self-loop term: weight di (weighted) or 1 (pre-scaled input)
    half4_t self = *(const half4_t*)&lin[(size_t)node * HH + fl];
    float sw = WEIGHTED ? di : 1.f;
    acc.x = fmaf(sw, (float)self.x, acc.x);
    acc.y = fmaf(sw, (float)self.y, acc.y);
    acc.z = fmaf(sw, (float)self.z, acc.z);
    acc.w = fmaf(sw, (float)self.w, acc.w);
    // bias + L2 norm + relu
    float4 b4 = *(const float4*)&b[fl];
    float4 v4 = make_float4(fmaf(di, acc.x, b4.x), fmaf(di, acc.y, b4.y),
                            fmaf(di, acc.z, b4.z), fmaf(di, acc.w, b4.w));
    float ss = v4.x * v4.x + v4.y * v4.y + v4.z * v4.z + v4.w * v4.w;
#pragma unroll
    for (int off = 1; off < 16; off <<= 1) ss += __shfl_xor(ss, off, 64);
    float inv = 1.f / fmaxf(sqrtf(ss), 1e-12f);
    v4.x = fmaxf(v4.x * inv, 0.f);
    v4.y = fmaxf(v4.y * inv, 0.f);
    v4.z = fmaxf(v4.z * inv, 0.f);
    v4.w = fmaxf(v4.w * inv, 0.f);
    if (q == 0) {
        if constexpr (HOUT) {
            half4_t o = {(half_t)v4.x, (half_t)v4.y, (half_t)v4.z, (half_t)v4.w};
            *(half4_t*)((half_t*)hout + (size_t)node * HH + fl) = o;
        } else {
            *(float4*)((float*)hout + (size_t)node * HH + fl) = v4;
        }
    }
}

// ---------------- pooling ----------------
__global__ __launch_bounds__(256) void k_pool(const float* __restrict__ node_emb,
                                              const int* __restrict__ batch,
                                              float* __restrict__ sums,
                                              float* __restrict__ cnts, int n) {
    const int NPW = 16;
    int wave = blockIdx.x * 4 + (threadIdx.x >> 6);
    int lane = threadIdx.x & 63;
    int start = wave * NPW;
    if (start >= n) return;
    int end = start + NPW; if (end > n) end = n;
    int cur = batch[start];
    float acc = 0.f;
    int runlen = 0;
    for (int node = start; node < end; ++node) {
        int g = batch[node];
        if (g != cur) {
            atomicAdd(&sums[(size_t)cur * HH + lane], acc);
            if (lane == 0) atomicAdd(&cnts[cur], (float)runlen);
            acc = 0.f; runlen = 0; cur = g;
        }
        acc += node_emb[(size_t)node * HH + lane];
        ++runlen;
    }
    atomicAdd(&sums[(size_t)cur * HH + lane], acc);
    if (lane == 0) atomicAdd(&cnts[cur], (float)runlen);
}

// ---------------- classifier + softmax ----------------
__global__ void k_final2(const float* __restrict__ sums, const float* __restrict__ cnts,
                         const float* __restrict__ Wm, const float* __restrict__ bm,
                         float* __restrict__ logits, float* __restrict__ probs,
                         float* __restrict__ graph_emb) {
    int g = blockIdx.x;
    int lane = threadIdx.x;
    float mean = sums[(size_t)g * HH + lane] / fmaxf(cnts[g], 1.0f);
    graph_emb[(size_t)g * HH + lane] = mean;

    __shared__ float semb[HH];
    __shared__ float slog[16];
    semb[lane] = mean;
    __syncthreads();
    if (lane < 10) {
        float acc = bm[lane];
        for (int k = 0; k < HH; ++k) acc = fmaf(semb[k], Wm[k * 10 + lane], acc);
        slog[lane] = acc;
    }
    __syncthreads();
    if (lane < 10) {
        float mx = -1e30f;
        for (int j = 0; j < 10; ++j) mx = fmaxf(mx, slog[j]);
        float den = 0.f;
        for (int j = 0; j < 10; ++j) den += __expf(slog[j] - mx);
        float lg = slog[lane];
        logits[g * 10 + lane] = lg;
        probs[g * 10 + lane] = __expf(lg - mx) / den;
    }
}

// ---------------- launch ----------------

extern "C" void kernel_launch(void* const* d_in, const int* in_sizes, int n_in,
                              void* d_out, int out_size, void* d_ws, size_t ws_size,
                              hipStream_t stream) {
    const float* x     = (const float*)d_in[0];
    const int*   ei    = (const int*)  d_in[1];
    const int*   batch = (const int*)  d_in[2];
    const float* W1 = (const float*)d_in[3];  const float* b1 = (const float*)d_in[4];
    const float* W2 = (const float*)d_in[5];  const float* b2 = (const float*)d_in[6];
    const float* W3 = (const float*)d_in[7];  const float* b3 = (const float*)d_in[8];
    const float* Wm = (const float*)d_in[9];  const float* bm = (const float*)d_in[10];

    const int N = in_sizes[2];
    const int E = in_sizes[1] / 2;
    const int G = (out_size - N * HH) / (2 * 10 + HH);
    const int NB = (N + BSZ - 1) >> BSH;     // buckets (196 for N=50000)

    const int* row = ei;
    const int* col = ei + E;

    float* out       = (float*)d_out;
    float* logits    = out;
    float* probs     = out + (size_t)G * 10;
    float* node_emb  = out + (size_t)2 * G * 10;
    float* graph_emb = node_emb + (size_t)N * HH;

    char* w = (char*)d_ws;
    auto alloc = [&](size_t bytes) { char* p = w; w += (bytes + 255) & ~(size_t)255; return p; };
    float* dinv    = (float*)alloc((size_t)N * 4);
    int*   cnt     = (int*)  alloc((size_t)N * 4);
    int*   rowptr  = (int*)  alloc((size_t)N * 4);
    int*   bucket_cnt    = (int*)alloc((size_t)(NB + 1) * 4);
    int*   bucket_base   = (int*)alloc((size_t)(NB + 1) * 4);
    int*   bucket_cursor = (int*)alloc((size_t)(NB + 1) * 4);
    float* sums    = (float*)alloc((size_t)G * HH * 4 + (size_t)G * 4);
    float* cnts    = sums + (size_t)G * HH;
    int*   pairbuf = (int*)  alloc((size_t)E * 4);
    int*   csr     = (int*)  alloc((size_t)E * 4);
    half_t* bufA   = (half_t*)alloc((size_t)N * HH * 2);
    half_t* bufB   = (half_t*)alloc((size_t)N * HH * 2);

    const int B = 256;
    dim3 blk(B);
    int node_blocks = (N + 3) / 4;
    int gemm_blocks = (N + 63) / 64;
    int poolN = G * HH + G;
    int initB = (poolN + B - 1) / B;
    int pool_blocks = (N + 63) / 64;

    // CSR build: LDS-binned hierarchical bucketing — no per-edge global atomics.
    k_init<<<initB, blk, 0, stream>>>(bucket_cnt, sums, NB, poolN);
    k_bhist<<<256, blk, 0, stream>>>(col, E, bucket_cnt, NB);
    k_bscan<<<1, blk, 0, stream>>>(bucket_cnt, bucket_base, bucket_cursor, NB);
    k_bscatter<<<256, blk, 0, stream>>>(row, col, E, bucket_cursor, pairbuf, NB);
    k_bcsr<<<NB, blk, 0, stream>>>(pairbuf, bucket_base, rowptr, cnt, dinv, csr, N);

    // layer 1: fp32 x -> fp16 lin (unscaled) -> weighted gather -> fp16 h1
    k_gemm<128, false, false, true><<<gemm_blocks, blk, 0, stream>>>(x, W1, dinv, bufA, N);
    k_gather_q<true, true><<<node_blocks, blk, 0, stream>>>(bufA, csr, rowptr, cnt, dinv, b1, bufB, N);
    // layer 2: fp16 h1 -> fp16 linS (pre-scaled) -> gather -> fp16 h2
    k_gemm<64, true, true, true><<<gemm_blocks, blk, 0, stream>>>(bufB, W2, dinv, bufA, N);
    k_gather_q<false, true><<<node_blocks, blk, 0, stream>>>(bufA, csr, rowptr, cnt, dinv, b2, bufB, N);
    // layer 3: fp16 h2 -> fp16 linS -> gather -> fp32 node_emb (output)
    k_gemm<64, true, true, true><<<gemm_blocks, blk, 0, stream>>>(bufB, W3, dinv, bufA, N);
    k_gather_q<false, false><<<node_blocks, blk, 0, stream>>>(bufA, csr, rowptr, cnt, dinv, b3, node_emb, N);

    // pool + classifier
    k_pool<<<pool_blocks, blk, 0, stream>>>(node_emb, batch, sums, cnts, N);
    k_final2<<<G, dim3(64), 0, stream>>>(sums, cnts, Wm, bm, logits, probs, graph_emb);
}